// Round 1
// baseline (609.720 us; speedup 1.0000x reference)
//
#include <hip/hip_runtime.h>
#include <stdint.h>

#define ROWS 8192   // B*N
#define N_ 512

typedef __attribute__((ext_vector_type(4))) float f32x4;
typedef __attribute__((ext_vector_type(8))) short s16x8;
typedef __attribute__((ext_vector_type(4))) short s16x4;
typedef __attribute__((ext_vector_type(8))) unsigned short u16x8;

__device__ __forceinline__ float bf2f(unsigned short h){
  union { unsigned int u; float f; } v; v.u = ((unsigned int)h) << 16; return v.f;
}
__device__ __forceinline__ unsigned short f2bf(float f){
  union { float f; unsigned int u; } v; v.f = f;
  unsigned int r = v.u + 0x7FFFu + ((v.u >> 16) & 1u);
  return (unsigned short)(r >> 16);
}
__device__ __forceinline__ float sigm(float x){ return 1.f / (1.f + __expf(-x)); }

// ---------------- weight prep ----------------
__global__ void k_transpose_cvt(const float* __restrict__ in, unsigned short* __restrict__ out,
                                int R, int C){
  __shared__ float t[32][33];
  int c0 = blockIdx.x*32, r0 = blockIdx.y*32;
  int tx = threadIdx.x & 31, ty = threadIdx.x >> 5;
  #pragma unroll
  for(int i=0;i<32;i+=8) t[ty+i][tx] = in[(size_t)(r0+ty+i)*C + c0+tx];
  __syncthreads();
  #pragma unroll
  for(int i=0;i<32;i+=8) out[(size_t)(c0+ty+i)*R + r0+tx] = f2bf(t[tx][ty+i]);
}

__global__ void k_cvt(const float* __restrict__ in, unsigned short* __restrict__ out, int n){
  int i = blockIdx.x*256 + threadIdx.x;
  if(i < n) out[i] = f2bf(in[i]);
}

// ---------------- LayerNorm (rows of 512) ----------------
template<int OUTF32>
__global__ void k_ln(const float* __restrict__ x, const float* __restrict__ gw,
                     const float* __restrict__ bw, void* __restrict__ outp){
  const int row = blockIdx.x*4 + (threadIdx.x >> 6);
  const int lane = threadIdx.x & 63;
  const f32x4* xr = (const f32x4*)(x + (size_t)row*512);
  f32x4 v0 = xr[lane], v1 = xr[lane + 64];
  float s  = v0[0]+v0[1]+v0[2]+v0[3] + v1[0]+v1[1]+v1[2]+v1[3];
  float s2 = v0[0]*v0[0]+v0[1]*v0[1]+v0[2]*v0[2]+v0[3]*v0[3]
           + v1[0]*v1[0]+v1[1]*v1[1]+v1[2]*v1[2]+v1[3]*v1[3];
  #pragma unroll
  for(int off=1; off<64; off<<=1){ s += __shfl_xor(s, off); s2 += __shfl_xor(s2, off); }
  float mean = s * (1.f/512.f);
  float inv = rsqrtf(s2*(1.f/512.f) - mean*mean + 1e-5f);
  const f32x4* gv = (const f32x4*)gw; const f32x4* bv = (const f32x4*)bw;
  f32x4 g0 = gv[lane], g1 = gv[lane+64], b0 = bv[lane], b1 = bv[lane+64];
  f32x4 o0, o1;
  #pragma unroll
  for(int e=0;e<4;e++){ o0[e] = (v0[e]-mean)*inv*g0[e] + b0[e];
                        o1[e] = (v1[e]-mean)*inv*g1[e] + b1[e]; }
  if(OUTF32){
    f32x4* op = (f32x4*)((float*)outp + (size_t)row*512);
    op[lane] = o0; op[lane+64] = o1;
  } else {
    unsigned short* ob = (unsigned short*)outp + (size_t)row*512;
    s16x4 h0, h1;
    #pragma unroll
    for(int e=0;e<4;e++){ h0[e] = (short)f2bf(o0[e]); h1[e] = (short)f2bf(o1[e]); }
    *(s16x4*)(ob + lane*4) = h0;
    *(s16x4*)(ob + 256 + lane*4) = h1;
  }
}

// ---------------- GEMM: C[M,N] = A[M,K] @ Bt[N,K]^T, bf16 in, fp32 acc ----------------
// EPI: 0=store bf16; 1=+bias,swish->bf16; 2=+bias,*0.5,+res->f32; 3=+res->f32;
//      4=+bias->bf16; 5=+bias,+res->f32
template<int EPI>
__global__ __launch_bounds__(256, 2)
void k_gemm(const unsigned short* __restrict__ A, const unsigned short* __restrict__ Bt,
            const float* __restrict__ bias, const float* __restrict__ res,
            void* __restrict__ outp, int M, int N, int K){
  __shared__ unsigned short As[128*64];
  __shared__ unsigned short Bs[128*64];
  const int tid = threadIdx.x, lane = tid & 63, wave = tid >> 6;
  const int m0 = blockIdx.y * 128, n0 = blockIdx.x * 128;
  const int wm = (wave >> 1) * 64, wn = (wave & 1) * 64;
  f32x4 acc[4][4];
  #pragma unroll
  for(int a=0;a<4;a++)
    #pragma unroll
    for(int b=0;b<4;b++) acc[a][b] = (f32x4){0.f,0.f,0.f,0.f};

  for(int kt = 0; kt < K; kt += 64){
    #pragma unroll
    for(int i=0;i<4;i++){
      int flat = i*256 + tid;
      int r = flat >> 3, c = flat & 7;
      int dst = r*64 + ((c ^ (r & 7)) << 3);
      *(u16x8*)(&As[dst]) = *(const u16x8*)(A + (size_t)(m0 + r)*K + kt + c*8);
      *(u16x8*)(&Bs[dst]) = *(const u16x8*)(Bt + (size_t)(n0 + r)*K + kt + c*8);
    }
    __syncthreads();
    #pragma unroll
    for(int ks=0; ks<2; ks++){
      s16x8 af[4], bfr[4];
      #pragma unroll
      for(int mi=0;mi<4;mi++){
        int row = wm + mi*16 + (lane & 15);
        int ch = (ks*4 + (lane >> 4)) ^ (row & 7);
        af[mi] = *(const s16x8*)(&As[row*64 + ch*8]);
      }
      #pragma unroll
      for(int ni=0;ni<4;ni++){
        int row = wn + ni*16 + (lane & 15);
        int ch = (ks*4 + (lane >> 4)) ^ (row & 7);
        bfr[ni] = *(const s16x8*)(&Bs[row*64 + ch*8]);
      }
      #pragma unroll
      for(int mi=0;mi<4;mi++)
        #pragma unroll
        for(int ni=0;ni<4;ni++)
          acc[mi][ni] = __builtin_amdgcn_mfma_f32_16x16x32_bf16(af[mi], bfr[ni], acc[mi][ni], 0, 0, 0);
    }
    __syncthreads();
  }
  const int rb = (lane >> 4) * 4, cb = lane & 15;
  #pragma unroll
  for(int mi=0;mi<4;mi++){
    #pragma unroll
    for(int ni=0;ni<4;ni++){
      int col = n0 + wn + ni*16 + cb;
      #pragma unroll
      for(int r=0;r<4;r++){
        int row = m0 + wm + mi*16 + rb + r;
        float v = acc[mi][ni][r];
        if(EPI==1||EPI==2||EPI==4||EPI==5) v += bias[col];
        if(EPI==2) v = 0.5f*v + res[(size_t)row*N + col];
        if(EPI==3||EPI==5) v += res[(size_t)row*N + col];
        if(EPI==1) v = v * sigm(v);
        if(EPI==0||EPI==1||EPI==4) ((unsigned short*)outp)[(size_t)row*N + col] = f2bf(v);
        else                        ((float*)outp)[(size_t)row*N + col] = v;
      }
    }
  }
}

// ---------------- fused attention with relative position ----------------
// grid (8 q-tiles, H=8, B=16), 4 waves; wave w owns q rows q0+16w..+15.
__global__ __launch_bounds__(256, 1)
void k_attn(const unsigned short* __restrict__ qkv, const unsigned short* __restrict__ emb,
            unsigned short* __restrict__ outb){
  __shared__ unsigned short Ks[512*64];   // swizzled K, later reused for P
  __shared__ unsigned short Vt[64*512];   // transposed+swizzled V
  const int tid = threadIdx.x, lane = tid & 63, w = tid >> 6;
  const int q0 = blockIdx.x * 64, h = blockIdx.y, b = blockIdx.z;

  #pragma unroll
  for(int i=0;i<16;i++){                  // K: 512x64 bf16
    int flat = i*256 + tid;
    int r = flat >> 3, c = flat & 7;
    *(u16x8*)(&Ks[r*64 + ((c ^ (r & 7)) << 3)]) =
      *(const u16x8*)(qkv + (size_t)(b*N_ + r)*1536 + 512 + h*64 + c*8);
  }
  #pragma unroll
  for(int i=0;i<16;i++){                  // V -> Vt[d][r] with r-swizzle
    int flat = i*256 + tid;
    int r = flat >> 3, c = flat & 7, d0 = c*8;
    u16x8 v = *(const u16x8*)(qkv + (size_t)(b*N_ + r)*1536 + 1024 + h*64 + d0);
    #pragma unroll
    for(int e=0;e<8;e++){
      int d = d0 + e;
      Vt[d*512 + (r ^ ((d & 7) << 3))] = v[e];
    }
  }
  __syncthreads();

  const int n0w = q0 + w*16;
  const int g = lane >> 4, j = lane & 15;
  s16x8 qf[2];
  #pragma unroll
  for(int ks=0;ks<2;ks++)
    qf[ks] = *(const s16x8*)(qkv + (size_t)(b*N_ + n0w + j)*1536 + h*64 + ks*32 + g*8);

  f32x4 sc[32];
  #pragma unroll
  for(int rt=0;rt<32;rt++) sc[rt] = (f32x4){0.f,0.f,0.f,0.f};

  #pragma unroll
  for(int rt=0;rt<32;rt++){
    #pragma unroll
    for(int ks=0;ks<2;ks++){
      int row = rt*16 + j;
      int ch = (ks*4 + g) ^ (row & 7);
      s16x8 kf = *(const s16x8*)(&Ks[row*64 + ch*8]);
      sc[rt] = __builtin_amdgcn_mfma_f32_16x16x32_bf16(qf[ks], kf, sc[rt], 0,0,0);
    }
    // rel-pos band: Paux[16,32] = Q16 @ e[cb-15 .. cb+16]^T ; pos[i,j] = Paux[i, i-j+15]
    int cb = n0w - rt*16 + 512;
    f32x4 pa0 = {0.f,0.f,0.f,0.f}, pa1 = {0.f,0.f,0.f,0.f};
    #pragma unroll
    for(int ks=0;ks<2;ks++){
      s16x8 e0 = *(const s16x8*)(emb + (size_t)(cb - 15 + j)*64 + ks*32 + g*8);
      s16x8 e1 = *(const s16x8*)(emb + (size_t)(cb + 1  + j)*64 + ks*32 + g*8);
      pa0 = __builtin_amdgcn_mfma_f32_16x16x32_bf16(qf[ks], e0, pa0, 0,0,0);
      pa1 = __builtin_amdgcn_mfma_f32_16x16x32_bf16(qf[ks], e1, pa1, 0,0,0);
    }
    #pragma unroll
    for(int reg=0;reg<4;reg++){
      int i_ = g*4 + reg;
      int m = i_ - j + 15;                 // in [0,30]
      int src = g*16 + (m & 15);
      float v0 = __shfl(pa0[reg], src);
      float v1 = __shfl(pa1[reg], src);
      sc[rt][reg] = (sc[rt][reg] + (m < 16 ? v0 : v1)) * 0.125f;
    }
  }
  // wave-parallel softmax over 512 cols (16 lanes x 32 tiles)
  float inv[4];
  #pragma unroll
  for(int reg=0;reg<4;reg++){
    float mx = -1e30f;
    #pragma unroll
    for(int rt=0;rt<32;rt++) mx = fmaxf(mx, sc[rt][reg]);
    #pragma unroll
    for(int off=1; off<16; off<<=1) mx = fmaxf(mx, __shfl_xor(mx, off));
    float sm = 0.f;
    #pragma unroll
    for(int rt=0;rt<32;rt++){ float e = __expf(sc[rt][reg] - mx); sc[rt][reg] = e; sm += e; }
    #pragma unroll
    for(int off=1; off<16; off<<=1) sm += __shfl_xor(sm, off);
    inv[reg] = 1.f / sm;
  }
  __syncthreads();                         // everyone done reading Ks
  unsigned short* Pw = &Ks[w * 8192];      // 16x512 bf16 per wave
  #pragma unroll
  for(int rt=0;rt<32;rt++){
    #pragma unroll
    for(int reg=0;reg<4;reg++){
      int i_ = g*4 + reg;
      int col = rt*16 + j;
      int ch = (col >> 3) ^ (i_ & 7);
      Pw[i_*512 + ch*8 + (col & 7)] = f2bf(sc[rt][reg] * inv[reg]);
    }
  }
  __syncthreads();
  f32x4 o[4];
  #pragma unroll
  for(int dt=0;dt<4;dt++) o[dt] = (f32x4){0.f,0.f,0.f,0.f};
  #pragma unroll
  for(int rt=0;rt<16;rt++){
    int ch = (rt*4 + g) ^ (j & 7);
    s16x8 pf = *(const s16x8*)(&Pw[j*512 + ch*8]);
    #pragma unroll
    for(int dt=0;dt<4;dt++){
      int d = dt*16 + j;
      int r0 = rt*32 + g*8;
      s16x8 vf = *(const s16x8*)(&Vt[d*512 + (r0 ^ ((d & 7) << 3))]);
      o[dt] = __builtin_amdgcn_mfma_f32_16x16x32_bf16(pf, vf, o[dt], 0,0,0);
    }
  }
  #pragma unroll
  for(int dt=0;dt<4;dt++)
    #pragma unroll
    for(int reg=0;reg<4;reg++)
      outb[(size_t)(b*N_ + n0w + g*4 + reg)*512 + h*64 + dt*16 + j] = f2bf(o[dt][reg]);
}

// ---------------- GLU ----------------
__global__ void k_glu(const unsigned short* __restrict__ hid, unsigned short* __restrict__ outp){
  size_t i = (size_t)blockIdx.x*256 + threadIdx.x;   // chunk of 8
  int row = (int)(i >> 7), cc = (int)(i & 127);
  u16x8 a  = *(const u16x8*)(hid + (size_t)row*2048 + cc*8);
  u16x8 gt = *(const u16x8*)(hid + (size_t)row*2048 + 1024 + cc*8);
  u16x8 o;
  #pragma unroll
  for(int e=0;e<8;e++){
    float av = bf2f(a[e]), gv = bf2f(gt[e]);
    o[e] = f2bf(av * sigm(gv));
  }
  *(u16x8*)(outp + (size_t)row*1024 + cc*8) = o;
}

// ---------------- depthwise conv 31 + BN + swish ----------------
__global__ __launch_bounds__(256, 2)
void k_dwconv(const unsigned short* __restrict__ gin, const float* __restrict__ dww,
              const float* __restrict__ dwb, const float* __restrict__ bng,
              const float* __restrict__ bnb, const float* __restrict__ bnm,
              const float* __restrict__ bnv, unsigned short* __restrict__ outp){
  __shared__ unsigned short gl[94][136];
  __shared__ float wl[31][128];
  const int c0 = blockIdx.x*128, n0 = blockIdx.y*64, b = blockIdx.z;
  const int tid = threadIdx.x;
  for(int i=0;i<6;i++){
    int flat = i*256 + tid;
    if(flat < 94*16){
      int r = flat >> 4, c = flat & 15;
      int n = n0 - 15 + r;
      u16x8 v = {0,0,0,0,0,0,0,0};
      if(n >= 0 && n < 512) v = *(const u16x8*)(gin + (size_t)(b*512 + n)*1024 + c0 + c*8);
      *(u16x8*)(&gl[r][c*8]) = v;
    }
  }
  for(int i=0;i<16;i++){
    int flat = i*256 + tid;
    if(flat < 31*128){
      int t = flat >> 7, cc = flat & 127;
      wl[t][cc] = dww[(size_t)(c0 + cc)*31 + t];
    }
  }
  __syncthreads();
  const int tc = tid & 31, tn = tid >> 5;
  f32x4 acc[8];
  #pragma unroll
  for(int nn=0;nn<8;nn++) acc[nn] = (f32x4){0.f,0.f,0.f,0.f};
  for(int t=0;t<31;t++){
    f32x4 wv = *(const f32x4*)(&wl[t][tc*4]);
    #pragma unroll
    for(int nn=0;nn<8;nn++){
      s16x4 gv = *(const s16x4*)(&gl[tn*8 + nn + t][tc*4]);
      f32x4 g4 = { bf2f((unsigned short)gv[0]), bf2f((unsigned short)gv[1]),
                   bf2f((unsigned short)gv[2]), bf2f((unsigned short)gv[3]) };
      acc[nn] += g4 * wv;
    }
  }
  #pragma unroll
  for(int e=0;e<4;e++){
    int c = c0 + tc*4 + e;
    float s  = bng[c] * rsqrtf(bnv[c] + 1e-5f);
    float sh = bnb[c] - bnm[c]*s;
    float db = dwb[c];
    #pragma unroll
    for(int nn=0;nn<8;nn++){
      float v = (acc[nn][e] + db)*s + sh;
      v = v * sigm(v);
      outp[(size_t)(b*512 + n0 + tn*8 + nn)*1024 + c] = f2bf(v);
    }
  }
}

// ---------------- launch ----------------
extern "C" void kernel_launch(void* const* d_in, const int* in_sizes, int n_in,
                              void* d_out, int out_size, void* d_ws, size_t ws_size,
                              hipStream_t stream){
  const float* x        = (const float*)d_in[0];
  const float* ff1_ln_g = (const float*)d_in[1];
  const float* ff1_ln_b = (const float*)d_in[2];
  const float* ff1_w1   = (const float*)d_in[3];
  const float* ff1_b1   = (const float*)d_in[4];
  const float* ff1_w2   = (const float*)d_in[5];
  const float* ff1_b2   = (const float*)d_in[6];
  const float* attn_ln_g= (const float*)d_in[7];
  const float* attn_ln_b= (const float*)d_in[8];
  const float* qkv_w    = (const float*)d_in[9];
  const float* out_w    = (const float*)d_in[10];
  const float* rel_emb  = (const float*)d_in[11];
  const float* conv_ln_g= (const float*)d_in[12];
  const float* conv_ln_b= (const float*)d_in[13];
  const float* pw1_w    = (const float*)d_in[14];
  const float* pw1_b    = (const float*)d_in[15];
  const float* dw_w     = (const float*)d_in[16];
  const float* dw_b     = (const float*)d_in[17];
  const float* bn_g     = (const float*)d_in[18];
  const float* bn_b     = (const float*)d_in[19];
  const float* bn_mean  = (const float*)d_in[20];
  const float* bn_var   = (const float*)d_in[21];
  const float* pw2_w    = (const float*)d_in[22];
  const float* pw2_b    = (const float*)d_in[23];
  const float* ff2_ln_g = (const float*)d_in[24];
  const float* ff2_ln_b = (const float*)d_in[25];
  const float* ff2_w1   = (const float*)d_in[26];
  const float* ff2_b1   = (const float*)d_in[27];
  const float* ff2_w2   = (const float*)d_in[28];
  const float* ff2_b2   = (const float*)d_in[29];
  const float* post_ln_g= (const float*)d_in[30];
  const float* post_ln_b= (const float*)d_in[31];
  (void)in_sizes; (void)n_in; (void)out_size; (void)ws_size;

  char* ws = (char*)d_ws;
  size_t off = 0;
  auto alloc = [&](size_t bytes)->char*{ char* p = ws + off; off += (bytes + 255) & ~(size_t)255; return p; };
  float*          res  = (float*)         alloc((size_t)ROWS*512*4);
  unsigned short* hbuf = (unsigned short*)alloc((size_t)ROWS*512*2);
  unsigned short* hid  = (unsigned short*)alloc((size_t)ROWS*2048*2);
  unsigned short* qkvb = (unsigned short*)alloc((size_t)ROWS*1536*2);
  unsigned short* glub = (unsigned short*)alloc((size_t)ROWS*1024*2);
  unsigned short* attnout = glub;   // alias: attn_out consumed before GLU is written
  unsigned short* dwout   = qkvb;   // alias: qkv consumed before dwconv output written
  unsigned short* w1t  = (unsigned short*)alloc((size_t)2048*512*2);
  unsigned short* w2t  = (unsigned short*)alloc((size_t)2048*512*2);
  unsigned short* qkvt = (unsigned short*)alloc((size_t)1536*512*2);
  unsigned short* outt = (unsigned short*)alloc((size_t)512*512*2);
  unsigned short* pw1c = (unsigned short*)alloc((size_t)2048*512*2);
  unsigned short* pw2c = (unsigned short*)alloc((size_t)512*1024*2);
  unsigned short* f2w1t= (unsigned short*)alloc((size_t)2048*512*2);
  unsigned short* f2w2t= (unsigned short*)alloc((size_t)2048*512*2);
  unsigned short* rele = (unsigned short*)alloc((size_t)1025*64*2);

  // weight prep (all -> bf16 [N][K])
  k_transpose_cvt<<<dim3(64, 16), 256, 0, stream>>>(ff1_w1, w1t, 512, 2048);
  k_transpose_cvt<<<dim3(16, 64), 256, 0, stream>>>(ff1_w2, w2t, 2048, 512);
  k_transpose_cvt<<<dim3(48, 16), 256, 0, stream>>>(qkv_w, qkvt, 512, 1536);
  k_transpose_cvt<<<dim3(16, 16), 256, 0, stream>>>(out_w, outt, 512, 512);
  k_transpose_cvt<<<dim3(64, 16), 256, 0, stream>>>(ff2_w1, f2w1t, 512, 2048);
  k_transpose_cvt<<<dim3(16, 64), 256, 0, stream>>>(ff2_w2, f2w2t, 2048, 512);
  k_cvt<<<2048*512/256, 256, 0, stream>>>(pw1_w, pw1c, 2048*512);
  k_cvt<<<512*1024/256, 256, 0, stream>>>(pw2_w, pw2c, 512*1024);
  k_cvt<<<(1025*64+255)/256, 256, 0, stream>>>(rel_emb, rele, 1025*64);

  // FF1 (x + 0.5*ff(x))
  k_ln<0><<<ROWS/4, 256, 0, stream>>>(x, ff1_ln_g, ff1_ln_b, hbuf);
  k_gemm<1><<<dim3(16, 64), 256, 0, stream>>>(hbuf, w1t, ff1_b1, nullptr, hid, ROWS, 2048, 512);
  k_gemm<2><<<dim3(4, 64), 256, 0, stream>>>(hid, w2t, ff1_b2, x, res, ROWS, 512, 2048);
  // attention
  k_ln<0><<<ROWS/4, 256, 0, stream>>>(res, attn_ln_g, attn_ln_b, hbuf);
  k_gemm<0><<<dim3(12, 64), 256, 0, stream>>>(hbuf, qkvt, nullptr, nullptr, qkvb, ROWS, 1536, 512);
  k_attn<<<dim3(8, 8, 16), 256, 0, stream>>>(qkvb, rele, attnout);
  k_gemm<3><<<dim3(4, 64), 256, 0, stream>>>(attnout, outt, nullptr, res, res, ROWS, 512, 512);
  // conv module
  k_ln<0><<<ROWS/4, 256, 0, stream>>>(res, conv_ln_g, conv_ln_b, hbuf);
  k_gemm<4><<<dim3(16, 64), 256, 0, stream>>>(hbuf, pw1c, pw1_b, nullptr, hid, ROWS, 2048, 512);
  k_glu<<<ROWS*128/256, 256, 0, stream>>>(hid, glub);
  k_dwconv<<<dim3(8, 8, 16), 256, 0, stream>>>(glub, dw_w, dw_b, bn_g, bn_b, bn_mean, bn_var, dwout);
  k_gemm<5><<<dim3(4, 64), 256, 0, stream>>>(dwout, pw2c, pw2_b, res, res, ROWS, 512, 1024);
  // FF2
  k_ln<0><<<ROWS/4, 256, 0, stream>>>(res, ff2_ln_g, ff2_ln_b, hbuf);
  k_gemm<1><<<dim3(16, 64), 256, 0, stream>>>(hbuf, f2w1t, ff2_b1, nullptr, hid, ROWS, 2048, 512);
  k_gemm<2><<<dim3(4, 64), 256, 0, stream>>>(hid, f2w2t, ff2_b2, res, res, ROWS, 512, 2048);
  // post-norm -> fp32 output
  k_ln<1><<<ROWS/4, 256, 0, stream>>>(res, post_ln_g, post_ln_b, d_out);
}

// Round 2
// 506.547 us; speedup vs baseline: 1.2037x; 1.2037x over previous
//
#include <hip/hip_runtime.h>
#include <stdint.h>

#define ROWS 8192   // B*N
#define N_ 512

typedef __attribute__((ext_vector_type(4))) float f32x4;
typedef __attribute__((ext_vector_type(8))) short s16x8;
typedef __attribute__((ext_vector_type(4))) short s16x4;
typedef __attribute__((ext_vector_type(8))) unsigned short u16x8;

__device__ __forceinline__ float bf2f(unsigned short h){
  union { unsigned int u; float f; } v; v.u = ((unsigned int)h) << 16; return v.f;
}
__device__ __forceinline__ unsigned short f2bf(float f){
  union { float f; unsigned int u; } v; v.f = f;
  unsigned int r = v.u + 0x7FFFu + ((v.u >> 16) & 1u);
  return (unsigned short)(r >> 16);
}
__device__ __forceinline__ float sigm(float x){ return 1.f / (1.f + __expf(-x)); }
__device__ __forceinline__ unsigned cvtpk(float lo, float hi){
  unsigned r;
  asm("v_cvt_pk_bf16_f32 %0, %1, %2" : "=v"(r) : "v"(lo), "v"(hi));
  return r;
}

// ---------------- weight prep ----------------
__global__ void k_transpose_cvt(const float* __restrict__ in, unsigned short* __restrict__ out,
                                int R, int C){
  __shared__ float t[32][33];
  int c0 = blockIdx.x*32, r0 = blockIdx.y*32;
  int tx = threadIdx.x & 31, ty = threadIdx.x >> 5;
  #pragma unroll
  for(int i=0;i<32;i+=8) t[ty+i][tx] = in[(size_t)(r0+ty+i)*C + c0+tx];
  __syncthreads();
  #pragma unroll
  for(int i=0;i<32;i+=8) out[(size_t)(c0+ty+i)*R + r0+tx] = f2bf(t[tx][ty+i]);
}

__global__ void k_cvt(const float* __restrict__ in, unsigned short* __restrict__ out, int n){
  int i = blockIdx.x*256 + threadIdx.x;
  if(i < n) out[i] = f2bf(in[i]);
}

// V tile transpose: qkv[b,n,1024+h*64+d] -> vt[(b*8+h)*64+d][n]
__global__ void k_vtrans(const unsigned short* __restrict__ qkv, unsigned short* __restrict__ vt){
  __shared__ unsigned short t[64][72];
  const int tid = threadIdx.x;
  const int n0 = blockIdx.x * 64;
  const int bh = blockIdx.y;
  const int b = bh >> 3, h = bh & 7;
  #pragma unroll
  for(int i=0;i<2;i++){
    int flat = i*256 + tid;
    int tok = flat >> 3, c = flat & 7;
    u16x8 v = *(const u16x8*)(qkv + (size_t)(b*N_ + n0 + tok)*1536 + 1024 + h*64 + c*8);
    *(u16x8*)(&t[tok][c*8]) = v;
  }
  __syncthreads();
  #pragma unroll
  for(int i=0;i<2;i++){
    int flat = i*256 + tid;
    int d = flat >> 3, tc = flat & 7;
    u16x8 o;
    #pragma unroll
    for(int e=0;e<8;e++) o[e] = t[tc*8+e][d];
    *(u16x8*)(vt + (((size_t)bh*64 + d) << 9) + n0 + tc*8) = o;
  }
}

// ---------------- LayerNorm (rows of 512) ----------------
template<int OUTF32>
__global__ void k_ln(const float* __restrict__ x, const float* __restrict__ gw,
                     const float* __restrict__ bw, void* __restrict__ outp){
  const int row = blockIdx.x*4 + (threadIdx.x >> 6);
  const int lane = threadIdx.x & 63;
  const f32x4* xr = (const f32x4*)(x + (size_t)row*512);
  f32x4 v0 = xr[lane], v1 = xr[lane + 64];
  float s  = v0[0]+v0[1]+v0[2]+v0[3] + v1[0]+v1[1]+v1[2]+v1[3];
  float s2 = v0[0]*v0[0]+v0[1]*v0[1]+v0[2]*v0[2]+v0[3]*v0[3]
           + v1[0]*v1[0]+v1[1]*v1[1]+v1[2]*v1[2]+v1[3]*v1[3];
  #pragma unroll
  for(int off=1; off<64; off<<=1){ s += __shfl_xor(s, off); s2 += __shfl_xor(s2, off); }
  float mean = s * (1.f/512.f);
  float inv = rsqrtf(s2*(1.f/512.f) - mean*mean + 1e-5f);
  const f32x4* gv = (const f32x4*)gw; const f32x4* bv = (const f32x4*)bw;
  f32x4 g0 = gv[lane], g1 = gv[lane+64], b0 = bv[lane], b1 = bv[lane+64];
  f32x4 o0, o1;
  #pragma unroll
  for(int e=0;e<4;e++){ o0[e] = (v0[e]-mean)*inv*g0[e] + b0[e];
                        o1[e] = (v1[e]-mean)*inv*g1[e] + b1[e]; }
  if(OUTF32){
    f32x4* op = (f32x4*)((float*)outp + (size_t)row*512);
    op[lane] = o0; op[lane+64] = o1;
  } else {
    unsigned short* ob = (unsigned short*)outp + (size_t)row*512;
    s16x4 h0, h1;
    #pragma unroll
    for(int e=0;e<4;e++){ h0[e] = (short)f2bf(o0[e]); h1[e] = (short)f2bf(o1[e]); }
    *(s16x4*)(ob + lane*4) = h0;
    *(s16x4*)(ob + 256 + lane*4) = h1;
  }
}

// ---------------- GEMM: C[M,N] = A[M,K] @ Bt[N,K]^T, bf16 in, fp32 acc ----------------
// EPI: 0=store bf16; 1=+bias,swish->bf16; 2=+bias,*0.5,+res->f32; 3=+res->f32;
//      4=+bias->bf16; 5=+bias,+res->f32
template<int EPI>
__global__ __launch_bounds__(256, 2)
void k_gemm(const unsigned short* __restrict__ A, const unsigned short* __restrict__ Bt,
            const float* __restrict__ bias, const float* __restrict__ res,
            void* __restrict__ outp, int M, int N, int K){
  __shared__ unsigned short As[128*64];
  __shared__ unsigned short Bs[128*64];
  const int tid = threadIdx.x, lane = tid & 63, wave = tid >> 6;
  // bijective XCD swizzle (m204)
  const int nwg = gridDim.x * gridDim.y;
  int orig = blockIdx.x + gridDim.x * blockIdx.y;
  int q8 = nwg >> 3, r8 = nwg & 7, xcd = orig & 7, idx = orig >> 3;
  int wg = (xcd < r8 ? xcd * (q8 + 1) : r8 * (q8 + 1) + (xcd - r8) * q8) + idx;
  const int m0 = (wg / gridDim.x) * 128, n0 = (wg % gridDim.x) * 128;
  const int wm = (wave >> 1) * 64, wn = (wave & 1) * 64;
  f32x4 acc[4][4];
  #pragma unroll
  for(int a=0;a<4;a++)
    #pragma unroll
    for(int b=0;b<4;b++) acc[a][b] = (f32x4){0.f,0.f,0.f,0.f};

  for(int kt = 0; kt < K; kt += 64){
    #pragma unroll
    for(int i=0;i<4;i++){
      int flat = i*256 + tid;
      int r = flat >> 3, c = flat & 7;
      int dst = r*64 + ((c ^ (r & 7)) << 3);
      *(u16x8*)(&As[dst]) = *(const u16x8*)(A + (size_t)(m0 + r)*K + kt + c*8);
      *(u16x8*)(&Bs[dst]) = *(const u16x8*)(Bt + (size_t)(n0 + r)*K + kt + c*8);
    }
    __syncthreads();
    #pragma unroll
    for(int ks=0; ks<2; ks++){
      s16x8 af[4], bfr[4];
      #pragma unroll
      for(int mi=0;mi<4;mi++){
        int row = wm + mi*16 + (lane & 15);
        int ch = (ks*4 + (lane >> 4)) ^ (row & 7);
        af[mi] = *(const s16x8*)(&As[row*64 + ch*8]);
      }
      #pragma unroll
      for(int ni=0;ni<4;ni++){
        int row = wn + ni*16 + (lane & 15);
        int ch = (ks*4 + (lane >> 4)) ^ (row & 7);
        bfr[ni] = *(const s16x8*)(&Bs[row*64 + ch*8]);
      }
      #pragma unroll
      for(int mi=0;mi<4;mi++)
        #pragma unroll
        for(int ni=0;ni<4;ni++)
          acc[mi][ni] = __builtin_amdgcn_mfma_f32_16x16x32_bf16(af[mi], bfr[ni], acc[mi][ni], 0, 0, 0);
    }
    __syncthreads();
  }
  const int rb = (lane >> 4) * 4, cb = lane & 15;
  #pragma unroll
  for(int mi=0;mi<4;mi++){
    #pragma unroll
    for(int ni=0;ni<4;ni++){
      int col = n0 + wn + ni*16 + cb;
      #pragma unroll
      for(int r=0;r<4;r++){
        int row = m0 + wm + mi*16 + rb + r;
        float v = acc[mi][ni][r];
        if(EPI==1||EPI==2||EPI==4||EPI==5) v += bias[col];
        if(EPI==2) v = 0.5f*v + res[(size_t)row*N + col];
        if(EPI==3||EPI==5) v += res[(size_t)row*N + col];
        if(EPI==1) v = v * sigm(v);
        if(EPI==0||EPI==1||EPI==4) ((unsigned short*)outp)[(size_t)row*N + col] = f2bf(v);
        else                        ((float*)outp)[(size_t)row*N + col] = v;
      }
    }
  }
}

// ---------------- fused attention with relative position (S^T, reg-resident P) ----
// grid (8 q-tiles, H=8, B=16), 4 waves; wave w owns q rows n0w..n0w+15.
__global__ __launch_bounds__(256, 2)
void k_attn(const unsigned short* __restrict__ qkv, const unsigned short* __restrict__ vt,
            const unsigned short* __restrict__ emb, unsigned short* __restrict__ outb){
  __shared__ unsigned short KV[512*64];   // K swizzled, then V^T swizzled
  const int tid = threadIdx.x, lane = tid & 63, w = tid >> 6;
  const int q0 = blockIdx.x * 64, h = blockIdx.y, b = blockIdx.z;
  const int j = lane & 15, g = lane >> 4;
  const int n0w = q0 + w*16;
  const size_t qkvbase = (size_t)b*N_*1536;

  // ---- stage K [512 r][64 ch], chunk ^= r&7 ----
  #pragma unroll
  for(int i=0;i<16;i++){
    int flat = i*256 + tid;
    int r = flat >> 3, c = flat & 7;
    *(u16x8*)(&KV[r*64 + ((c ^ (r & 7)) << 3)]) =
      *(const u16x8*)(qkv + qkvbase + (size_t)r*1536 + 512 + h*64 + c*8);
  }
  // Q fragment: lane (j,g) holds Q[n0w+j][ks*32+g*8+e]  (A- and B-frag compatible)
  s16x8 qf[2];
  #pragma unroll
  for(int ks=0;ks<2;ks++)
    qf[ks] = *(const s16x8*)(qkv + qkvbase + (size_t)(n0w + j)*1536 + h*64 + ks*32 + g*8);
  // init pa1: band rows n0w+513+jj  (= pa0 of virtual rt=-1)
  f32x4 pa1 = {0.f,0.f,0.f,0.f};
  #pragma unroll
  for(int ks=0;ks<2;ks++){
    s16x8 e1 = *(const s16x8*)(emb + (size_t)(n0w + 513 + j)*64 + ks*32 + g*8);
    pa1 = __builtin_amdgcn_mfma_f32_16x16x32_bf16(e1, qf[ks], pa1, 0,0,0);
  }
  __syncthreads();

  // ---- S^T: lane (j,g) reg holds raw S[q=n0w+j][r=rt*16+g*4+reg] + pos ----
  f32x4 sc[32];
  #pragma unroll
  for(int rt=0;rt<32;rt++){
    const int cb = n0w - rt*16 + 512;
    f32x4 s   = {0.f,0.f,0.f,0.f};
    f32x4 pa0 = {0.f,0.f,0.f,0.f};
    #pragma unroll
    for(int ks=0;ks<2;ks++){
      int row = rt*16 + j;
      int ch = (ks*4 + g) ^ (row & 7);
      s16x8 kf = *(const s16x8*)(&KV[row*64 + (ch<<3)]);
      s = __builtin_amdgcn_mfma_f32_16x16x32_bf16(kf, qf[ks], s, 0,0,0);
      s16x8 e0 = *(const s16x8*)(emb + (size_t)(cb - 15 + j)*64 + ks*32 + g*8);
      pa0 = __builtin_amdgcn_mfma_f32_16x16x32_bf16(e0, qf[ks], pa0, 0,0,0);
    }
    // paT layout: lane (j', g') reg holds Paux[q=j'][jj=g'*4+reg]
    // target needs Paux[q=j][m], m = j+15-(g*4+reg); elem (m&3) from lane j+16*((m&15)>>2)
    #pragma unroll
    for(int reg=0;reg<4;reg++){
      int elem = (j + 3 - reg) & 3;
      float s0 = (elem & 2) ? ((elem & 1) ? pa0[3] : pa0[2]) : ((elem & 1) ? pa0[1] : pa0[0]);
      float s1 = (elem & 2) ? ((elem & 1) ? pa1[3] : pa1[2]) : ((elem & 1) ? pa1[1] : pa1[0]);
      int m = j + 15 - g*4 - reg;
      int src = j + (((m & 15) >> 2) << 4);
      float v0 = __shfl(s0, src);
      float v1 = __shfl(s1, src);
      sc[rt][reg] = s[reg] + (m < 16 ? v0 : v1);
    }
    pa1 = pa0;   // band overlap: pa1(rt+1) == pa0(rt)
  }
  __syncthreads();                         // all waves done reading K

  // ---- stage V^T [64 d][512 r], r-chunk ^= d&7 ----
  #pragma unroll
  for(int i=0;i<16;i++){
    int flat = i*256 + tid;
    int d = flat >> 6, rc = flat & 63;
    u16x8 v = *(const u16x8*)(vt + (((size_t)(b*8 + h)*64 + d) << 9) + rc*8);
    *(u16x8*)(&KV[d*512 + ((rc ^ (d & 7)) << 3)]) = v;
  }

  // ---- softmax (register-only), scale 1/8 folded into exp2 const ----
  const float C2 = 0.125f * 1.4426950408889634f;
  float mx = -1e30f;
  #pragma unroll
  for(int rt=0;rt<32;rt++)
    mx = fmaxf(mx, fmaxf(fmaxf(sc[rt][0], sc[rt][1]), fmaxf(sc[rt][2], sc[rt][3])));
  mx = fmaxf(mx, __shfl_xor(mx, 16));
  mx = fmaxf(mx, __shfl_xor(mx, 32));
  const float mc = mx * C2;
  float sm = 0.f;
  unsigned w0[32], w1[32];
  #pragma unroll
  for(int rt=0;rt<32;rt++){
    float p0 = exp2f(fmaf(sc[rt][0], C2, -mc));
    float p1 = exp2f(fmaf(sc[rt][1], C2, -mc));
    float p2 = exp2f(fmaf(sc[rt][2], C2, -mc));
    float p3 = exp2f(fmaf(sc[rt][3], C2, -mc));
    sm += (p0 + p1) + (p2 + p3);
    w0[rt] = cvtpk(p0, p1);
    w1[rt] = cvtpk(p2, p3);
  }
  sm += __shfl_xor(sm, 16);
  sm += __shfl_xor(sm, 32);
  float inv = 1.f / sm;
  __syncthreads();                         // V staged

  // ---- PV: A-frag built by cross-lane gather of packed P ----
  f32x4 o[4];
  #pragma unroll
  for(int dt=0;dt<4;dt++) o[dt] = (f32x4){0.f,0.f,0.f,0.f};
  const int srcA = j + ((g & 1) << 5);
  const int srcB = srcA + 16;
  const bool hi = (g >= 2);
  #pragma unroll
  for(int rts=0; rts<16; rts++){
    unsigned a0 = __shfl(w0[2*rts],   srcA);
    unsigned a1 = __shfl(w1[2*rts],   srcA);
    unsigned a2 = __shfl(w0[2*rts],   srcB);
    unsigned a3 = __shfl(w1[2*rts],   srcB);
    unsigned b0 = __shfl(w0[2*rts+1], srcA);
    unsigned b1 = __shfl(w1[2*rts+1], srcA);
    unsigned b2 = __shfl(w0[2*rts+1], srcB);
    unsigned b3 = __shfl(w1[2*rts+1], srcB);
    union { unsigned u[4]; s16x8 v; } pu;
    pu.u[0] = hi ? b0 : a0;
    pu.u[1] = hi ? b1 : a1;
    pu.u[2] = hi ? b2 : a2;
    pu.u[3] = hi ? b3 : a3;
    #pragma unroll
    for(int dt=0;dt<4;dt++){
      int d = dt*16 + j;
      int ch = (rts*4 + g) ^ (d & 7);
      s16x8 vf = *(const s16x8*)(&KV[d*512 + (ch<<3)]);
      o[dt] = __builtin_amdgcn_mfma_f32_16x16x32_bf16(pu.v, vf, o[dt], 0,0,0);
    }
  }
  // epilogue: fold 1/sum, write
  #pragma unroll
  for(int reg=0;reg<4;reg++){
    float invq = __shfl(inv, (g<<2) + reg);
    int tok = n0w + (g<<2) + reg;
    #pragma unroll
    for(int dt=0;dt<4;dt++)
      outb[(size_t)(b*N_ + tok)*512 + h*64 + dt*16 + j] = f2bf(o[dt][reg] * invq);
  }
}

// ---------------- GLU ----------------
__global__ void k_glu(const unsigned short* __restrict__ hid, unsigned short* __restrict__ outp){
  size_t i = (size_t)blockIdx.x*256 + threadIdx.x;   // chunk of 8
  int row = (int)(i >> 7), cc = (int)(i & 127);
  u16x8 a  = *(const u16x8*)(hid + (size_t)row*2048 + cc*8);
  u16x8 gt = *(const u16x8*)(hid + (size_t)row*2048 + 1024 + cc*8);
  u16x8 o;
  #pragma unroll
  for(int e=0;e<8;e++){
    float av = bf2f(a[e]), gv = bf2f(gt[e]);
    o[e] = f2bf(av * sigm(gv));
  }
  *(u16x8*)(outp + (size_t)row*1024 + cc*8) = o;
}

// ---------------- depthwise conv 31 + BN + swish ----------------
__global__ __launch_bounds__(256, 2)
void k_dwconv(const unsigned short* __restrict__ gin, const float* __restrict__ dww,
              const float* __restrict__ dwb, const float* __restrict__ bng,
              const float* __restrict__ bnb, const float* __restrict__ bnm,
              const float* __restrict__ bnv, unsigned short* __restrict__ outp){
  __shared__ unsigned short gl[94][136];
  __shared__ float wl[31][128];
  const int c0 = blockIdx.x*128, n0 = blockIdx.y*64, b = blockIdx.z;
  const int tid = threadIdx.x;
  for(int i=0;i<6;i++){
    int flat = i*256 + tid;
    if(flat < 94*16){
      int r = flat >> 4, c = flat & 15;
      int n = n0 - 15 + r;
      u16x8 v = {0,0,0,0,0,0,0,0};
      if(n >= 0 && n < 512) v = *(const u16x8*)(gin + (size_t)(b*512 + n)*1024 + c0 + c*8);
      *(u16x8*)(&gl[r][c*8]) = v;
    }
  }
  for(int i=0;i<16;i++){
    int flat = i*256 + tid;
    if(flat < 31*128){
      int t = flat >> 7, cc = flat & 127;
      wl[t][cc] = dww[(size_t)(c0 + cc)*31 + t];
    }
  }
  __syncthreads();
  const int tc = tid & 31, tn = tid >> 5;
  f32x4 acc[8];
  #pragma unroll
  for(int nn=0;nn<8;nn++) acc[nn] = (f32x4){0.f,0.f,0.f,0.f};
  for(int t=0;t<31;t++){
    f32x4 wv = *(const f32x4*)(&wl[t][tc*4]);
    #pragma unroll
    for(int nn=0;nn<8;nn++){
      s16x4 gv = *(const s16x4*)(&gl[tn*8 + nn + t][tc*4]);
      f32x4 g4 = { bf2f((unsigned short)gv[0]), bf2f((unsigned short)gv[1]),
                   bf2f((unsigned short)gv[2]), bf2f((unsigned short)gv[3]) };
      acc[nn] += g4 * wv;
    }
  }
  #pragma unroll
  for(int e=0;e<4;e++){
    int c = c0 + tc*4 + e;
    float s  = bng[c] * rsqrtf(bnv[c] + 1e-5f);
    float sh = bnb[c] - bnm[c]*s;
    float db = dwb[c];
    #pragma unroll
    for(int nn=0;nn<8;nn++){
      float v = (acc[nn][e] + db)*s + sh;
      v = v * sigm(v);
      outp[(size_t)(b*512 + n0 + tn*8 + nn)*1024 + c] = f2bf(v);
    }
  }
}

// ---------------- launch ----------------
extern "C" void kernel_launch(void* const* d_in, const int* in_sizes, int n_in,
                              void* d_out, int out_size, void* d_ws, size_t ws_size,
                              hipStream_t stream){
  const float* x        = (const float*)d_in[0];
  const float* ff1_ln_g = (const float*)d_in[1];
  const float* ff1_ln_b = (const float*)d_in[2];
  const float* ff1_w1   = (const float*)d_in[3];
  const float* ff1_b1   = (const float*)d_in[4];
  const float* ff1_w2   = (const float*)d_in[5];
  const float* ff1_b2   = (const float*)d_in[6];
  const float* attn_ln_g= (const float*)d_in[7];
  const float* attn_ln_b= (const float*)d_in[8];
  const float* qkv_w    = (const float*)d_in[9];
  const float* out_w    = (const float*)d_in[10];
  const float* rel_emb  = (const float*)d_in[11];
  const float* conv_ln_g= (const float*)d_in[12];
  const float* conv_ln_b= (const float*)d_in[13];
  const float* pw1_w    = (const float*)d_in[14];
  const float* pw1_b    = (const float*)d_in[15];
  const float* dw_w     = (const float*)d_in[16];
  const float* dw_b     = (const float*)d_in[17];
  const float* bn_g     = (const float*)d_in[18];
  const float* bn_b     = (const float*)d_in[19];
  const float* bn_mean  = (const float*)d_in[20];
  const float* bn_var   = (const float*)d_in[21];
  const float* pw2_w    = (const float*)d_in[22];
  const float* pw2_b    = (const float*)d_in[23];
  const float* ff2_ln_g = (const float*)d_in[24];
  const float* ff2_ln_b = (const float*)d_in[25];
  const float* ff2_w1   = (const float*)d_in[26];
  const float* ff2_b1   = (const float*)d_in[27];
  const float* ff2_w2   = (const float*)d_in[28];
  const float* ff2_b2   = (const float*)d_in[29];
  const float* post_ln_g= (const float*)d_in[30];
  const float* post_ln_b= (const float*)d_in[31];
  (void)in_sizes; (void)n_in; (void)out_size; (void)ws_size;

  char* ws = (char*)d_ws;
  size_t off = 0;
  auto alloc = [&](size_t bytes)->char*{ char* p = ws + off; off += (bytes + 255) & ~(size_t)255; return p; };
  float*          res  = (float*)         alloc((size_t)ROWS*512*4);
  unsigned short* hbuf = (unsigned short*)alloc((size_t)ROWS*512*2);
  unsigned short* hid  = (unsigned short*)alloc((size_t)ROWS*2048*2);
  unsigned short* qkvb = (unsigned short*)alloc((size_t)ROWS*1536*2);
  unsigned short* glub = (unsigned short*)alloc((size_t)ROWS*1024*2);
  unsigned short* attnout = glub;   // alias: attn_out consumed before GLU is written
  unsigned short* dwout   = qkvb;   // alias: qkv consumed before dwconv output written
  unsigned short* vtb     = hid;    // alias: hid free between FF1 and conv module
  unsigned short* w1t  = (unsigned short*)alloc((size_t)2048*512*2);
  unsigned short* w2t  = (unsigned short*)alloc((size_t)2048*512*2);
  unsigned short* qkvt = (unsigned short*)alloc((size_t)1536*512*2);
  unsigned short* outt = (unsigned short*)alloc((size_t)512*512*2);
  unsigned short* pw1c = (unsigned short*)alloc((size_t)2048*512*2);
  unsigned short* pw2c = (unsigned short*)alloc((size_t)512*1024*2);
  unsigned short* f2w1t= (unsigned short*)alloc((size_t)2048*512*2);
  unsigned short* f2w2t= (unsigned short*)alloc((size_t)2048*512*2);
  unsigned short* rele = (unsigned short*)alloc((size_t)1025*64*2);

  // weight prep (all -> bf16 [N][K])
  k_transpose_cvt<<<dim3(64, 16), 256, 0, stream>>>(ff1_w1, w1t, 512, 2048);
  k_transpose_cvt<<<dim3(16, 64), 256, 0, stream>>>(ff1_w2, w2t, 2048, 512);
  k_transpose_cvt<<<dim3(48, 16), 256, 0, stream>>>(qkv_w, qkvt, 512, 1536);
  k_transpose_cvt<<<dim3(16, 16), 256, 0, stream>>>(out_w, outt, 512, 512);
  k_transpose_cvt<<<dim3(64, 16), 256, 0, stream>>>(ff2_w1, f2w1t, 512, 2048);
  k_transpose_cvt<<<dim3(16, 64), 256, 0, stream>>>(ff2_w2, f2w2t, 2048, 512);
  k_cvt<<<2048*512/256, 256, 0, stream>>>(pw1_w, pw1c, 2048*512);
  k_cvt<<<512*1024/256, 256, 0, stream>>>(pw2_w, pw2c, 512*1024);
  k_cvt<<<(1025*64+255)/256, 256, 0, stream>>>(rel_emb, rele, 1025*64);

  // FF1 (x + 0.5*ff(x))
  k_ln<0><<<ROWS/4, 256, 0, stream>>>(x, ff1_ln_g, ff1_ln_b, hbuf);
  k_gemm<1><<<dim3(16, 64), 256, 0, stream>>>(hbuf, w1t, ff1_b1, nullptr, hid, ROWS, 2048, 512);
  k_gemm<2><<<dim3(4, 64), 256, 0, stream>>>(hid, w2t, ff1_b2, x, res, ROWS, 512, 2048);
  // attention
  k_ln<0><<<ROWS/4, 256, 0, stream>>>(res, attn_ln_g, attn_ln_b, hbuf);
  k_gemm<0><<<dim3(12, 64), 256, 0, stream>>>(hbuf, qkvt, nullptr, nullptr, qkvb, ROWS, 1536, 512);
  k_vtrans<<<dim3(8, 128), 256, 0, stream>>>(qkvb, vtb);
  k_attn<<<dim3(8, 8, 16), 256, 0, stream>>>(qkvb, vtb, rele, attnout);
  k_gemm<3><<<dim3(4, 64), 256, 0, stream>>>(attnout, outt, nullptr, res, res, ROWS, 512, 512);
  // conv module
  k_ln<0><<<ROWS/4, 256, 0, stream>>>(res, conv_ln_g, conv_ln_b, hbuf);
  k_gemm<4><<<dim3(16, 64), 256, 0, stream>>>(hbuf, pw1c, pw1_b, nullptr, hid, ROWS, 2048, 512);
  k_glu<<<ROWS*128/256, 256, 0, stream>>>(hid, glub);
  k_dwconv<<<dim3(8, 8, 16), 256, 0, stream>>>(glub, dw_w, dw_b, bn_g, bn_b, bn_mean, bn_var, dwout);
  k_gemm<5><<<dim3(4, 64), 256, 0, stream>>>(dwout, pw2c, pw2_b, res, res, ROWS, 512, 1024);
  // FF2
  k_ln<0><<<ROWS/4, 256, 0, stream>>>(res, ff2_ln_g, ff2_ln_b, hbuf);
  k_gemm<1><<<dim3(16, 64), 256, 0, stream>>>(hbuf, f2w1t, ff2_b1, nullptr, hid, ROWS, 2048, 512);
  k_gemm<2><<<dim3(4, 64), 256, 0, stream>>>(hid, f2w2t, ff2_b2, res, res, ROWS, 512, 2048);
  // post-norm -> fp32 output
  k_ln<1><<<ROWS/4, 256, 0, stream>>>(res, post_ln_g, post_ln_b, d_out);
}